// Round 4
// baseline (512.171 us; speedup 1.0000x reference)
//
#include <hip/hip_runtime.h>

// RK4 point-mass rollout: 65536 independent chains × 256 sequential steps.
// One thread per chain (65536 threads = 1024 waves = 1 wave/SIMD on 256 CUs).
// Memory-bound (~402 MB total traffic, ~64 us floor @ 6.3 TB/s); compute is
// ~4x under the floor. Latency hidden by register double-buffering of the
// action stream (next 128 B chunk issued before computing current chunk).

static constexpr int STEPS = 256;
static constexpr int UN    = 16;          // steps per chunk
static constexpr int NCH   = STEPS / UN;  // 16 chunks
static constexpr int F4    = UN / 2;      // 8 x 16B of actions per chunk

// native vector type — required by __builtin_nontemporal_load (HIP_vector_type is not)
typedef float f32x4 __attribute__((ext_vector_type(4)));

__device__ __forceinline__ void accel2(float vx, float vy, float th, float tq,
                                       float& ax, float& ay) {
    // reference: dir = v / max(|v|, 1e-6); perp = (-dir.y, dir.x)
    // a = th*dir + tq*perp = inv * [[th,-tq],[tq,th]] * v
    float n2 = vx * vx + vy * vy;
    float r  = __builtin_amdgcn_rsqf(n2);
    r = r * (1.5f - 0.5f * n2 * r * r);          // one Newton step -> ~fp32 exact
    float inv = (n2 >= 1e-12f) ? r : 1e6f;       // matches max(norm,1e-6) guard
    ax = inv * (th * vx - tq * vy);
    ay = inv * (th * vy + tq * vx);
}

__global__ __launch_bounds__(256, 1)
void rk4_rollout(const float4* __restrict__ init,
                 const f32x4* __restrict__ act,
                 float4* __restrict__ out) {
    const int e = blockIdx.x * 256 + threadIdx.x;

    const float dt   = 1.0f / 30.0f;
    const float hdt  = 0.5f * dt;
    const float dt6  = dt / 6.0f;
    const float dt26 = dt * dt / 6.0f;

    float4 st = init[e];
    float px = st.x, py = st.y, vx = st.z, vy = st.w;

    const f32x4* a4 = act + (size_t)e * (STEPS / 2);  // 2 steps per 16B
    float4*      o4 = out + (size_t)e * STEPS;        // 1 step  per 16B

    f32x4 cur[F4], nxt[F4];
#pragma unroll
    for (int j = 0; j < F4; ++j) cur[j] = __builtin_nontemporal_load(&a4[j]);

#pragma unroll 1
    for (int c = 0; c < NCH; ++c) {
        // prefetch next chunk's actions while computing this one (uniform branch)
        if (c + 1 < NCH) {
#pragma unroll
            for (int j = 0; j < F4; ++j)
                nxt[j] = __builtin_nontemporal_load(&a4[(c + 1) * F4 + j]);
        }

        float4* oc = o4 + c * UN;

#pragma unroll
        for (int s = 0; s < UN; ++s) {
            f32x4 q  = cur[s >> 1];
            float th = (s & 1) ? q.z : q.x;   // thrust
            float tq = (s & 1) ? q.w : q.y;   // torque

            float a1x, a1y, a2x, a2y, a3x, a3y, a4x_, a4y_;
            accel2(vx, vy, th, tq, a1x, a1y);
            float v2x = vx + hdt * a1x;
            float v2y = vy + hdt * a1y;
            accel2(v2x, v2y, th, tq, a2x, a2y);
            float v3x = vx + hdt * a2x;
            float v3y = vy + hdt * a2y;
            accel2(v3x, v3y, th, tq, a3x, a3y);
            float v4x = vx + dt * a3x;
            float v4y = vy + dt * a3y;
            accel2(v4x, v4y, th, tq, a4x_, a4y_);

            // pos uses OLD vel: dp-weighted sum collapses to 6*vel + dt*(a1+a2+a3)
            px += dt * vx + dt26 * (a1x + a2x + a3x);
            py += dt * vy + dt26 * (a1y + a2y + a3y);
            vx += dt6 * (a1x + 2.0f * (a2x + a3x) + a4x_);
            vy += dt6 * (a1y + 2.0f * (a2y + a3y) + a4y_);

            oc[s] = make_float4(px, py, vx, vy);
        }

#pragma unroll
        for (int j = 0; j < F4; ++j) cur[j] = nxt[j];
    }
}

extern "C" void kernel_launch(void* const* d_in, const int* in_sizes, int n_in,
                              void* d_out, int out_size, void* d_ws, size_t ws_size,
                              hipStream_t stream) {
    const float4* init = (const float4*)d_in[0];   // (65536, 4) f32
    const f32x4*  act  = (const f32x4*)d_in[1];    // (65536, 256, 2) f32
    float4*       out  = (float4*)d_out;           // (65536, 256, 4) f32

    const int n_elem = in_sizes[0] / 4;            // 65536
    rk4_rollout<<<n_elem / 256, 256, 0, stream>>>(init, act, out);
}

// Round 5
// 477.306 us; speedup vs baseline: 1.0730x; 1.0730x over previous
//
#include <hip/hip_runtime.h>

// RK4 point-mass rollout: 65536 independent chains × 256 sequential steps.
// One thread per chain (1024 waves = 1 wave/SIMD, occupancy is structural).
// Round-4 lesson: VGPR_Count=48 proved the compiler collapsed the array-based
// double buffer and sank loads to just-before-use -> latency-bound at 2.4 TB/s
// (30% HBM), 17% VALU. This version pins the pipeline with NAMED register
// buffers (no arrays, no copy loop): compute chunk c from A, refill A with
// c+2 (WAR dep pins placement), compute c+1 from B, refill B with c+3.
// sched_barrier(ALU) fences stop VMEM from crossing. Plain (cached) loads:
// actions fit L3 (128 MiB < 256 MiB) and are re-staged by the harness.

static constexpr int STEPS = 256;
static constexpr int UN    = 8;           // steps per chunk
static constexpr int NF    = UN / 2;      // 4 x 16B action vectors per chunk
static constexpr int NCH   = STEPS / UN;  // 32 chunks

typedef float f32x4 __attribute__((ext_vector_type(4)));

__device__ __forceinline__ void accel2(float vx, float vy, float th, float tq,
                                       float& ax, float& ay) {
    // reference: dir = v / max(|v|, 1e-6); perp = (-dir.y, dir.x)
    // a = th*dir + tq*perp = inv * [[th,-tq],[tq,th]] * v
    float n2 = vx * vx + vy * vy;
    float r  = __builtin_amdgcn_rsqf(n2);
    r = r * (1.5f - 0.5f * n2 * r * r);          // one Newton step -> ~fp32 exact
    float inv = (n2 >= 1e-12f) ? r : 1e6f;       // matches max(norm,1e-6) guard
    ax = inv * (th * vx - tq * vy);
    ay = inv * (th * vy + tq * vx);
}

__device__ __forceinline__ void rk4_step(float& px, float& py, float& vx, float& vy,
                                         float th, float tq, float4* o) {
    const float dt   = 1.0f / 30.0f;
    const float hdt  = 0.5f * dt;
    const float dt6  = dt / 6.0f;
    const float dt26 = dt * dt / 6.0f;

    float a1x, a1y, a2x, a2y, a3x, a3y, a4x, a4y;
    accel2(vx, vy, th, tq, a1x, a1y);
    accel2(vx + hdt * a1x, vy + hdt * a1y, th, tq, a2x, a2y);
    accel2(vx + hdt * a2x, vy + hdt * a2y, th, tq, a3x, a3y);
    accel2(vx + dt  * a3x, vy + dt  * a3y, th, tq, a4x, a4y);

    // pos uses OLD vel: dp-weighted sum collapses to 6*vel + dt*(a1+a2+a3)
    px += dt * vx + dt26 * (a1x + a2x + a3x);
    py += dt * vy + dt26 * (a1y + a2y + a3y);
    vx += dt6 * (a1x + 2.0f * (a2x + a3x) + a4x);
    vy += dt6 * (a1y + 2.0f * (a2y + a3y) + a4y);

    *o = make_float4(px, py, vx, vy);
}

__device__ __forceinline__ void step_pair(float& px, float& py, float& vx, float& vy,
                                          f32x4 q, float4* o) {
    rk4_step(px, py, vx, vy, q.x, q.y, o);
    rk4_step(px, py, vx, vy, q.z, q.w, o + 1);
}

__device__ __forceinline__ void chunk8(float& px, float& py, float& vx, float& vy,
                                       f32x4 q0, f32x4 q1, f32x4 q2, f32x4 q3,
                                       float4* oc) {
    step_pair(px, py, vx, vy, q0, oc);
    step_pair(px, py, vx, vy, q1, oc + 2);
    step_pair(px, py, vx, vy, q2, oc + 4);
    step_pair(px, py, vx, vy, q3, oc + 6);
}

__global__ __launch_bounds__(256, 1)
void rk4_rollout(const float4* __restrict__ init,
                 const f32x4* __restrict__ act,
                 float4* __restrict__ out) {
    const int e = blockIdx.x * 256 + threadIdx.x;

    float4 st = init[e];
    float px = st.x, py = st.y, vx = st.z, vy = st.w;

    const f32x4* a4 = act + (size_t)e * (STEPS / 2);  // 2 steps per 16B
    float4*      o4 = out + (size_t)e * STEPS;

    // two NAMED register buffers — no arrays, no copy loop
    f32x4 A0 = a4[0], A1 = a4[1], A2 = a4[2], A3 = a4[3];   // chunk 0
    f32x4 B0 = a4[4], B1 = a4[5], B2 = a4[6], B3 = a4[7];   // chunk 1

#pragma unroll 1
    for (int c = 0; c < NCH; c += 2) {
        float4* oc = o4 + c * UN;

        chunk8(px, py, vx, vy, A0, A1, A2, A3, oc);
        if (c + 2 < NCH) {          // refill A with chunk c+2 (WAR pins placement)
            const f32x4* p = a4 + (c + 2) * NF;
            A0 = p[0]; A1 = p[1]; A2 = p[2]; A3 = p[3];
        }
        __builtin_amdgcn_sched_barrier(0x1);   // ALU may cross; VMEM may not sink

        chunk8(px, py, vx, vy, B0, B1, B2, B3, oc + UN);
        if (c + 3 < NCH) {          // refill B with chunk c+3
            const f32x4* p = a4 + (c + 3) * NF;
            B0 = p[0]; B1 = p[1]; B2 = p[2]; B3 = p[3];
        }
        __builtin_amdgcn_sched_barrier(0x1);
    }
}

extern "C" void kernel_launch(void* const* d_in, const int* in_sizes, int n_in,
                              void* d_out, int out_size, void* d_ws, size_t ws_size,
                              hipStream_t stream) {
    const float4* init = (const float4*)d_in[0];   // (65536, 4) f32
    const f32x4*  act  = (const f32x4*)d_in[1];    // (65536, 256, 2) f32
    float4*       out  = (float4*)d_out;           // (65536, 256, 4) f32

    const int n_elem = in_sizes[0] / 4;            // 65536
    rk4_rollout<<<n_elem / 256, 256, 0, stream>>>(init, act, out);
}

// Round 6
// 399.692 us; speedup vs baseline: 1.2814x; 1.1942x over previous
//
#include <hip/hip_runtime.h>

// RK4 point-mass rollout: 65536 chains x 256 sequential steps, 1 thread/chain.
// ROUND-5 LESSON (counters): WRITE_SIZE 1.48x inflated, 2.6 TB/s, VALU 17% --
// the kernel was UNCOALESCED: per-thread-contiguous streams scatter each wave
// instruction across 64 cache lines (4KB lane stride). Prefetch tricks were
// irrelevant. This version stages BOTH streams through LDS so every global
// instruction is lane-adjacent = address-adjacent (full 128B lines):
//   - actions: coalesced 64B/chain tile loads -> LDS (XOR swizzle) -> own chain
//   - output:  states -> LDS -> coalesced 128B/chain tile drain
// Action staging is double-buffered: loads issued before compute, consumed
// after the drain (two barriers of separation hide ~900cy HBM latency).

typedef float f32x4 __attribute__((ext_vector_type(4)));

static constexpr int STEPS = 256;
static constexpr int T     = 8;            // steps per tile
static constexpr int NT    = STEPS / T;    // 32 tiles
static constexpr int B     = 256;          // threads = chains per block

__device__ __forceinline__ void accel2(float vx, float vy, float th, float tq,
                                       float& ax, float& ay) {
    // dir = v / max(|v|,1e-6); perp = (-dir.y, dir.x); a = th*dir + tq*perp
    float n2 = vx * vx + vy * vy;
    float r  = __builtin_amdgcn_rsqf(n2);
    r = r * (1.5f - 0.5f * n2 * r * r);          // Newton step -> ~fp32 exact
    float inv = (n2 >= 1e-12f) ? r : 1e6f;
    ax = inv * (th * vx - tq * vy);
    ay = inv * (th * vy + tq * vx);
}

__device__ __forceinline__ void rk4_step(float& px, float& py, float& vx, float& vy,
                                         float th, float tq) {
    const float dt = 1.0f / 30.0f, hdt = 0.5f * dt;
    const float dt6 = dt / 6.0f,  dt26 = dt * dt / 6.0f;
    float a1x, a1y, a2x, a2y, a3x, a3y, a4x, a4y;
    accel2(vx, vy, th, tq, a1x, a1y);
    accel2(vx + hdt * a1x, vy + hdt * a1y, th, tq, a2x, a2y);
    accel2(vx + hdt * a2x, vy + hdt * a2y, th, tq, a3x, a3y);
    accel2(vx + dt  * a3x, vy + dt  * a3y, th, tq, a4x, a4y);
    // pos uses OLD vel: dp-weighted sum collapses to 6*vel + dt*(a1+a2+a3)
    px += dt * vx + dt26 * (a1x + a2x + a3x);
    py += dt * vy + dt26 * (a1y + a2y + a3y);
    vx += dt6 * (a1x + 2.0f * (a2x + a3x) + a4x);
    vy += dt6 * (a1y + 2.0f * (a2y + a3y) + a4y);
}

__global__ __launch_bounds__(B, 1)
void rk4_rollout(const float4* __restrict__ init,
                 const f32x4* g_act,    // no __restrict__: stores may alias ->
                 f32x4*       g_out) {  // loads cannot sink below the drain
    __shared__ f32x4 s_act[2][B * T / 2];   // 2 x 16 KiB (16B unit = 2 steps)
    __shared__ f32x4 s_out[B * T];          // 32 KiB     (16B unit = 1 step)

    const int tid = threadIdx.x;
    const int cb  = blockIdx.x * B;

    const f32x4* gA = g_act + (size_t)cb * (STEPS / 2);  // 128 units per chain
    f32x4*       gO = g_out + (size_t)cb * STEPS;        // 256 units per chain

    float4 st = init[cb + tid];
    float px = st.x, py = st.y, vx = st.z, vy = st.w;

    const int i0 = tid, i1 = tid + B, i2 = tid + 2 * B, i3 = tid + 3 * B;
    // load mapping: item i -> chain i>>2, slot i&3 (tile = 4 x 16B per chain)
    const int c0 = i0 >> 2, s0 = i0 & 3;
    const int c1 = i1 >> 2, s1 = i1 & 3;
    const int c2 = i2 >> 2, s2 = i2 & 3;
    const int c3 = i3 >> 2, s3 = i3 & 3;
    // XOR-swizzled LDS slots (8 lanes per 16B bank-span — structural min for b128)
    const int w0 = c0 * 4 + (s0 ^ (c0 & 3));
    const int w1 = c1 * 4 + (s1 ^ (c1 & 3));
    const int w2 = c2 * 4 + (s2 ^ (c2 & 3));
    const int w3 = c3 * 4 + (s3 ^ (c3 & 3));

    f32x4 r0, r1, r2, r3;

    // ---- prologue: stage tile 0 ----
    r0 = gA[c0 * 128 + s0];
    r1 = gA[c1 * 128 + s1];
    r2 = gA[c2 * 128 + s2];
    r3 = gA[c3 * 128 + s3];
    s_act[0][w0] = r0;
    s_act[0][w1] = r1;
    s_act[0][w2] = r2;
    s_act[0][w3] = r3;
    __syncthreads();

#pragma unroll 1
    for (int t = 0; t < NT; ++t) {
        const int cur = t & 1, nxt = cur ^ 1;

        // issue next tile's loads now (unconditional, clamped -> same BB)
        {
            const int tb = (t + 1 < NT ? t + 1 : t) * 4;
            r0 = gA[c0 * 128 + tb + s0];
            r1 = gA[c1 * 128 + tb + s1];
            r2 = gA[c2 * 128 + tb + s2];
            r3 = gA[c3 * 128 + tb + s3];
        }
        __builtin_amdgcn_sched_barrier(0);   // pin load issue before compute

        // ---- compute 8 steps from s_act[cur]; states -> s_out ----
#pragma unroll
        for (int j = 0; j < 4; ++j) {
            f32x4 q = s_act[cur][tid * 4 + (j ^ (tid & 3))];
            rk4_step(px, py, vx, vy, q.x, q.y);
            s_out[tid * 8 + ((2 * j)     ^ (tid & 7))] = (f32x4){px, py, vx, vy};
            rk4_step(px, py, vx, vy, q.z, q.w);
            s_out[tid * 8 + ((2 * j + 1) ^ (tid & 7))] = (f32x4){px, py, vx, vy};
        }
        __syncthreads();

        // ---- drain s_out -> global: 8 lanes x 16B = one chain's 128B slab ----
#pragma unroll
        for (int k = 0; k < 8; ++k) {
            const int it = tid + k * B;
            const int ch = it >> 3, sl = it & 7;
            f32x4 v = s_out[ch * 8 + (sl ^ (ch & 7))];
            gO[ch * 256 + t * 8 + sl] = v;
        }

        // ---- stage next tile's actions (loads completed long ago) ----
        s_act[nxt][w0] = r0;
        s_act[nxt][w1] = r1;
        s_act[nxt][w2] = r2;
        s_act[nxt][w3] = r3;
        __syncthreads();
    }
}

extern "C" void kernel_launch(void* const* d_in, const int* in_sizes, int n_in,
                              void* d_out, int out_size, void* d_ws, size_t ws_size,
                              hipStream_t stream) {
    const float4* init = (const float4*)d_in[0];   // (65536, 4) f32
    const f32x4*  act  = (const f32x4*)d_in[1];    // (65536, 256, 2) f32
    f32x4*        out  = (f32x4*)d_out;            // (65536, 256, 4) f32

    const int n_elem = in_sizes[0] / 4;            // 65536
    rk4_rollout<<<n_elem / B, B, 0, stream>>>(init, act, out);
}